// Round 2
// baseline (1112.062 us; speedup 1.0000x reference)
//
#include <hip/hip_runtime.h>
#include <hip/hip_bf16.h>
#include <stdint.h>

#define BB 8
#define LL 4096
#define DD 64

typedef short bf16x8 __attribute__((ext_vector_type(8)));
typedef float f32x4 __attribute__((ext_vector_type(4)));

__device__ inline short f2bfs(float x) {
    __hip_bfloat16 h = __float2bfloat16(x);
    return __builtin_bit_cast(short, h);
}

__device__ inline bf16x8 pack8(const float* p) {
    float4 a = *(const float4*)p;
    float4 b = *(const float4*)(p + 4);
    bf16x8 r;
    r[0] = f2bfs(a.x); r[1] = f2bfs(a.y); r[2] = f2bfs(a.z); r[3] = f2bfs(a.w);
    r[4] = f2bfs(b.x); r[5] = f2bfs(b.y); r[6] = f2bfs(b.z); r[7] = f2bfs(b.w);
    return r;
}

__global__ void detect_mask_kernel(const uint32_t* __restrict__ w, uint32_t* __restrict__ flag) {
    __shared__ int nonbin;
    if (threadIdx.x == 0) nonbin = 0;
    __syncthreads();
    int bad = 0;
    for (int i = threadIdx.x; i < 4096; i += 256) bad |= (w[i] > 1u) ? 1 : 0;
    if (bad) atomicOr(&nonbin, 1);
    __syncthreads();
    if (threadIdx.x == 0) *flag = (uint32_t)(nonbin != 0);
}

// One block = 64 q-rows of one batch. 256 threads = 4 waves.
// Pass 1: QK^T (MFMA bf16) + exp row-sums in registers (no LDS, no barriers).
// Pass 2: recompute QK^T, write normalized attn (f32), P->bf16 via swizzled LDS,
//         PV MFMA with V fragments loaded straight from global (d-split by wave).
__global__ __launch_bounds__(256) void fused_attn_kernel(
    const float* __restrict__ qg, const float* __restrict__ kg,
    const float* __restrict__ vg, const void* __restrict__ maskv,
    const uint32_t* __restrict__ flagp,
    float* __restrict__ attn, float* __restrict__ outp)
{
    __shared__ alignas(16) ushort Ps[64 * 64];   // bf16 P tile, chunk-XOR swizzled
    const int tid = (int)threadIdx.x;
    const int w   = tid >> 6;          // wave 0..3
    const int l   = tid & 63;
    const int lr  = l & 15, lg = l >> 4;
    const int id  = (int)blockIdx.x;   // id = qt*8 + b  -> batch b on XCD b
    const int b   = id & 7;
    const int q0  = (id >> 3) * 64;
    const bool mbyte = (*flagp != 0);
    const uint8_t* m8  = (const uint8_t*)maskv + (size_t)b * LL * LL;
    const int*     m32 = (const int*)maskv     + (size_t)b * LL * LL;

    // Q A-fragments for this wave's 16 q-rows (row = lr, d-block = lg*8, s*32)
    bf16x8 qf[2];
    {
        const float* qrow = qg + (size_t)(b * LL + q0 + 16 * w + lr) * DD;
        qf[0] = pack8(qrow + lg * 8);
        qf[1] = pack8(qrow + 32 + lg * 8);
    }
    const float* kb = kg + (size_t)b * LL * DD;
    const float* vb = vg + (size_t)b * LL * DD;

    // per-lane C-frag row offsets into this batch's mask / attn
    uint32_t mrow[4];
    #pragma unroll
    for (int r = 0; r < 4; ++r)
        mrow[r] = (uint32_t)(q0 + 16 * w + lg * 4 + r) * LL;

    // ---------------- pass 1: exp row sums ----------------
    float rsum[4] = {0.f, 0.f, 0.f, 0.f};
    for (int kt = 0; kt < LL / 64; ++kt) {
        const int kbase = kt * 64;
        #pragma unroll
        for (int n = 0; n < 4; ++n) {
            const float* kr0 = kb + (size_t)(kbase + n * 16 + lr) * DD + lg * 8;
            f32x4 c = {0.f, 0.f, 0.f, 0.f};
            c = __builtin_amdgcn_mfma_f32_16x16x32_bf16(qf[0], pack8(kr0), c, 0, 0, 0);
            c = __builtin_amdgcn_mfma_f32_16x16x32_bf16(qf[1], pack8(kr0 + 32), c, 0, 0, 0);
            const uint32_t mc = (uint32_t)(kbase + n * 16 + lr);
            #pragma unroll
            for (int r = 0; r < 4; ++r) {
                int mk = mbyte ? (int)m8[mrow[r] + mc] : m32[mrow[r] + mc];
                float p = mk ? 0.f : __expf(c[r] * 0.125f);
                rsum[r] += p;
            }
        }
    }
    #pragma unroll
    for (int off = 1; off < 16; off <<= 1)
        #pragma unroll
        for (int r = 0; r < 4; ++r)
            rsum[r] += __shfl_xor(rsum[r], off, 64);
    float rinv[4];
    #pragma unroll
    for (int r = 0; r < 4; ++r) rinv[r] = 1.0f / rsum[r];

    // ---------------- pass 2: attn write + PV ----------------
    f32x4 oacc[4];
    #pragma unroll
    for (int mt = 0; mt < 4; ++mt) { f32x4 z = {0.f, 0.f, 0.f, 0.f}; oacc[mt] = z; }
    float* attnb = attn + (size_t)b * LL * LL;

    for (int kt = 0; kt < LL / 64; ++kt) {
        const int kbase = kt * 64;

        // V B-fragments for this wave's d-slice [16w,16w+16), issued early
        bf16x8 vf[2];
        #pragma unroll
        for (int s2 = 0; s2 < 2; ++s2) {
            float tv[8];
            #pragma unroll
            for (int j = 0; j < 8; ++j)
                tv[j] = vb[(size_t)(kbase + s2 * 32 + lg * 8 + j) * DD + 16 * w + lr];
            bf16x8 vv;
            #pragma unroll
            for (int j = 0; j < 8; ++j) vv[j] = f2bfs(tv[j]);
            vf[s2] = vv;
        }

        // QK^T, mask, exp, normalize, write attn + swizzled LDS (bf16)
        #pragma unroll
        for (int n = 0; n < 4; ++n) {
            const float* kr0 = kb + (size_t)(kbase + n * 16 + lr) * DD + lg * 8;
            f32x4 c = {0.f, 0.f, 0.f, 0.f};
            c = __builtin_amdgcn_mfma_f32_16x16x32_bf16(qf[0], pack8(kr0), c, 0, 0, 0);
            c = __builtin_amdgcn_mfma_f32_16x16x32_bf16(qf[1], pack8(kr0 + 32), c, 0, 0, 0);
            const uint32_t mc = (uint32_t)(kbase + n * 16 + lr);
            #pragma unroll
            for (int r = 0; r < 4; ++r) {
                int mk = mbyte ? (int)m8[mrow[r] + mc] : m32[mrow[r] + mc];
                float p = mk ? 0.f : __expf(c[r] * 0.125f) * rinv[r];
                attnb[(size_t)mrow[r] + mc] = p;
                const int row = 16 * w + lg * 4 + r;
                const int col = n * 16 + lr;
                const int swz = (row & 7) ^ (((row >> 3) & 1) << 1);
                Ps[(row << 6) + (((col >> 3) ^ swz) << 3) + (col & 7)] = (ushort)f2bfs(p);
            }
        }
        __syncthreads();

        // PV: A = P rows (all 64 q), B = V (this wave's 16 d cols)
        #pragma unroll
        for (int mt = 0; mt < 4; ++mt) {
            #pragma unroll
            for (int s2 = 0; s2 < 2; ++s2) {
                const int row = mt * 16 + lr;
                const int swz = (row & 7) ^ (((row >> 3) & 1) << 1);
                bf16x8 pa = *(const bf16x8*)&Ps[(row << 6) + ((((s2 << 2) + lg) ^ swz) << 3)];
                oacc[mt] = __builtin_amdgcn_mfma_f32_16x16x32_bf16(pa, vf[s2], oacc[mt], 0, 0, 0);
            }
        }
        __syncthreads();
    }

    #pragma unroll
    for (int mt = 0; mt < 4; ++mt)
        #pragma unroll
        for (int r = 0; r < 4; ++r)
            outp[(size_t)(b * LL + q0 + mt * 16 + lg * 4 + r) * DD + 16 * w + lr] = oacc[mt][r];
}

extern "C" void kernel_launch(void* const* d_in, const int* in_sizes, int n_in,
                              void* d_out, int out_size, void* d_ws, size_t ws_size,
                              hipStream_t stream) {
    const float* q = (const float*)d_in[0];
    const float* k = (const float*)d_in[1];
    const float* v = (const float*)d_in[2];
    const void* mask = d_in[3];
    float* attn = (float*)d_out;
    float* outp = attn + (size_t)BB * LL * LL;
    uint32_t* flagp = (uint32_t*)d_ws;

    detect_mask_kernel<<<1, 256, 0, stream>>>((const uint32_t*)mask, flagp);
    fused_attn_kernel<<<dim3((LL / 64) * BB), 256, 0, stream>>>(q, k, v, mask, flagp, attn, outp);
}

// Round 4
// 381.688 us; speedup vs baseline: 2.9135x; 2.9135x over previous
//
#include <hip/hip_runtime.h>
#include <hip/hip_bf16.h>
#include <stdint.h>

#define BB 8
#define LL 4096
#define DD 64
#define NT (LL / 64)   // 64 k-tiles of 64 columns

typedef short bf16x8 __attribute__((ext_vector_type(8)));
typedef float f32x4 __attribute__((ext_vector_type(4)));

__device__ inline short f2bfs(float x) {
    __hip_bfloat16 h = __float2bfloat16(x);
    return __builtin_bit_cast(short, h);
}

__device__ inline bf16x8 pack8(const float* p) {
    float4 a = *(const float4*)p;
    float4 b = *(const float4*)(p + 4);
    bf16x8 r;
    r[0] = f2bfs(a.x); r[1] = f2bfs(a.y); r[2] = f2bfs(a.z); r[3] = f2bfs(a.w);
    r[4] = f2bfs(b.x); r[5] = f2bfs(b.y); r[6] = f2bfs(b.z); r[7] = f2bfs(b.w);
    return r;
}

__device__ inline bf16x8 pack8v(float4 a, float4 b) {
    bf16x8 r;
    r[0] = f2bfs(a.x); r[1] = f2bfs(a.y); r[2] = f2bfs(a.z); r[3] = f2bfs(a.w);
    r[4] = f2bfs(b.x); r[5] = f2bfs(b.y); r[6] = f2bfs(b.z); r[7] = f2bfs(b.w);
    return r;
}

__device__ inline int swzf(int row) { return (row & 7) ^ ((row >> 3) & 7); }

__global__ void detect_mask_kernel(const uint32_t* __restrict__ w, uint32_t* __restrict__ flag) {
    __shared__ int nonbin;
    if (threadIdx.x == 0) nonbin = 0;
    __syncthreads();
    int bad = 0;
    for (int i = threadIdx.x; i < 4096; i += 256) bad |= (w[i] > 1u) ? 1 : 0;
    if (bad) atomicOr(&nonbin, 1);
    __syncthreads();
    if (threadIdx.x == 0) *flag = (uint32_t)(nonbin != 0);
}

// One block = 64 q-rows of one batch. 256 threads = 4 waves, each wave owns 16 q-rows
// (QK^T) and a 16-wide d-slice (PV). Pass 1: QK^T (MFMA, K LDS-staged dbuf) + exp row
// sums; mask read once, per-lane bits cached in LDS. Pass 2: recompute QK^T, write
// normalized attn, P->bf16 swizzled LDS, PV MFMA with V^T LDS-staged dbuf.
__global__ __launch_bounds__(256, 2) void fused_attn_kernel(
    const float* __restrict__ qg, const float* __restrict__ kg,
    const float* __restrict__ vg, const void* __restrict__ maskv,
    const uint32_t* __restrict__ flagp,
    float* __restrict__ attn, float* __restrict__ outp)
{
    __shared__ alignas(16) ushort Kt[2][64 * 64];   // bf16 K tile   [krow][d]  (swizzled 16B chunks)
    __shared__ alignas(16) ushort Vt[2][64 * 64];   // bf16 V^T tile [d][krow]  (swizzled)
    __shared__ alignas(16) ushort Ps[64 * 64];      // bf16 P tile   [q][k]     (swizzled)
    __shared__ ushort Msk[4][NT][64];               // per-lane mask bits: [wave][tile][lane]

    const int tid = (int)threadIdx.x;
    const int w   = tid >> 6;            // wave 0..3
    const int l   = tid & 63;
    const int lr  = l & 15, lg = l >> 4;
    const int id  = (int)blockIdx.x;     // id = qt*8 + b
    const int b   = id & 7;
    const int q0  = (id >> 3) * 64;
    const bool mbyte = (*flagp != 0);
    const uint8_t* m8  = (const uint8_t*)maskv + (size_t)b * LL * LL;
    const int*     m32 = (const int*)maskv     + (size_t)b * LL * LL;

    const float* kb = kg + (size_t)b * LL * DD;
    const float* vb = vg + (size_t)b * LL * DD;
    float* attnb = attn + (size_t)b * LL * LL;

    // Q A-fragments (persistent): wave's rows 16w+lr, k-offsets lg*8 (+32)
    bf16x8 qf[2];
    {
        const float* qrow = qg + (size_t)(b * LL + q0 + 16 * w + lr) * DD;
        qf[0] = pack8(qrow + lg * 8);
        qf[1] = pack8(qrow + 32 + lg * 8);
    }

    uint32_t mrow[4];
    #pragma unroll
    for (int r = 0; r < 4; ++r)
        mrow[r] = (uint32_t)(q0 + 16 * w + lg * 4 + r) * LL;

    // ---- staging helpers (regs across compute, commit at end of body) ----
    const int krow0 = tid >> 3, kc8 = tid & 7;      // K: 2 chunks/thread
    float4 ka[4];
    auto kissue = [&](int kbase) {
        const float* p0 = kb + (size_t)(kbase + krow0) * DD + kc8 * 8;
        ka[0] = *(const float4*)p0;
        ka[1] = *(const float4*)(p0 + 4);
        const float* p1 = p0 + 32 * DD;
        ka[2] = *(const float4*)p1;
        ka[3] = *(const float4*)(p1 + 4);
    };
    auto kcommit = [&](int buf) {
        *(bf16x8*)&Kt[buf][krow0 * 64 + (kc8 ^ swzf(krow0)) * 8] = pack8v(ka[0], ka[1]);
        const int r1 = krow0 + 32;
        *(bf16x8*)&Kt[buf][r1 * 64 + (kc8 ^ swzf(r1)) * 8] = pack8v(ka[2], ka[3]);
    };
    const int vkk0 = tid >> 4, vc4 = tid & 15;      // V: 4 float4/thread, transposed commit
    float4 va[4];
    auto vissue = [&](int kbase) {
        #pragma unroll
        for (int it = 0; it < 4; ++it)
            va[it] = *(const float4*)(vb + (size_t)(kbase + vkk0 + it * 16) * DD + vc4 * 4);
    };
    auto vcommit = [&](int buf) {
        #pragma unroll
        for (int it = 0; it < 4; ++it) {
            const int kk = vkk0 + it * 16;
            float vv[4] = {va[it].x, va[it].y, va[it].z, va[it].w};
            #pragma unroll
            for (int e = 0; e < 4; ++e) {
                const int d = vc4 * 4 + e;
                Vt[buf][d * 64 + ((kk >> 3) ^ swzf(d)) * 8 + (kk & 7)] = (ushort)f2bfs(vv[e]);
            }
        }
    };

    // ================= pass 1: exp row sums + mask bit cache =================
    float rsum[4] = {0.f, 0.f, 0.f, 0.f};
    kissue(0);
    kcommit(0);
    __syncthreads();
    #pragma unroll 1
    for (int kt = 0; kt < NT; ++kt) {
        const int cur = kt & 1, kbase = kt * 64;
        if (kt < NT - 1) kissue(kbase + 64);
        ushort mbit = 0;
        #pragma unroll
        for (int n = 0; n < 4; ++n) {
            const int kr = n * 16 + lr;
            bf16x8 k0 = *(const bf16x8*)&Kt[cur][kr * 64 + ((lg)     ^ swzf(kr)) * 8];
            bf16x8 k1 = *(const bf16x8*)&Kt[cur][kr * 64 + ((4 + lg) ^ swzf(kr)) * 8];
            f32x4 c = {0.f, 0.f, 0.f, 0.f};
            c = __builtin_amdgcn_mfma_f32_16x16x32_bf16(qf[0], k0, c, 0, 0, 0);
            c = __builtin_amdgcn_mfma_f32_16x16x32_bf16(qf[1], k1, c, 0, 0, 0);
            const uint32_t mc = (uint32_t)(kbase + n * 16 + lr);
            #pragma unroll
            for (int r = 0; r < 4; ++r) {
                const int mk = mbyte ? (int)m8[mrow[r] + mc] : m32[mrow[r] + mc];
                mbit |= (ushort)((mk ? 1 : 0) << (n * 4 + r));
                float p = mk ? 0.f : __expf(c[r] * 0.125f);
                rsum[r] += p;
            }
        }
        Msk[w][kt][l] = mbit;
        if (kt < NT - 1) kcommit(cur ^ 1);
        __syncthreads();
    }

    #pragma unroll
    for (int off = 1; off < 16; off <<= 1)
        #pragma unroll
        for (int r = 0; r < 4; ++r)
            rsum[r] += __shfl_xor(rsum[r], off, 64);
    float rinv[4];
    #pragma unroll
    for (int r = 0; r < 4; ++r) rinv[r] = 1.0f / rsum[r];

    // ================= pass 2: attn write + PV =================
    f32x4 oacc[4];
    #pragma unroll
    for (int mt = 0; mt < 4; ++mt) { f32x4 z = {0.f, 0.f, 0.f, 0.f}; oacc[mt] = z; }

    kissue(0);
    vissue(0);
    kcommit(0);
    vcommit(0);
    __syncthreads();
    #pragma unroll 1
    for (int kt = 0; kt < NT; ++kt) {
        const int cur = kt & 1, kbase = kt * 64;
        if (kt < NT - 1) { kissue(kbase + 64); vissue(kbase + 64); }
        const int mbit = (int)Msk[w][kt][l];
        #pragma unroll
        for (int n = 0; n < 4; ++n) {
            const int kr = n * 16 + lr;
            bf16x8 k0 = *(const bf16x8*)&Kt[cur][kr * 64 + ((lg)     ^ swzf(kr)) * 8];
            bf16x8 k1 = *(const bf16x8*)&Kt[cur][kr * 64 + ((4 + lg) ^ swzf(kr)) * 8];
            f32x4 c = {0.f, 0.f, 0.f, 0.f};
            c = __builtin_amdgcn_mfma_f32_16x16x32_bf16(qf[0], k0, c, 0, 0, 0);
            c = __builtin_amdgcn_mfma_f32_16x16x32_bf16(qf[1], k1, c, 0, 0, 0);
            const uint32_t mc = (uint32_t)(kbase + n * 16 + lr);
            #pragma unroll
            for (int r = 0; r < 4; ++r) {
                const int mk = (mbit >> (n * 4 + r)) & 1;
                float p = mk ? 0.f : __expf(c[r] * 0.125f) * rinv[r];
                attnb[mrow[r] + mc] = p;
                const int row = 16 * w + lg * 4 + r;
                const int col = n * 16 + lr;
                Ps[row * 64 + (((col >> 3) ^ swzf(row))) * 8 + (col & 7)] = (ushort)f2bfs(p);
            }
        }
        __syncthreads();   // A: Ps complete; Vt[cur] ready from previous iteration

        {
            const int vrow = 16 * w + lr;
            bf16x8 vf0 = *(const bf16x8*)&Vt[cur][vrow * 64 + ((lg)     ^ swzf(vrow)) * 8];
            bf16x8 vf1 = *(const bf16x8*)&Vt[cur][vrow * 64 + ((4 + lg) ^ swzf(vrow)) * 8];
            #pragma unroll
            for (int mt = 0; mt < 4; ++mt) {
                const int prow = mt * 16 + lr;
                bf16x8 pa0 = *(const bf16x8*)&Ps[prow * 64 + ((lg)     ^ swzf(prow)) * 8];
                bf16x8 pa1 = *(const bf16x8*)&Ps[prow * 64 + ((4 + lg) ^ swzf(prow)) * 8];
                oacc[mt] = __builtin_amdgcn_mfma_f32_16x16x32_bf16(pa0, vf0, oacc[mt], 0, 0, 0);
                oacc[mt] = __builtin_amdgcn_mfma_f32_16x16x32_bf16(pa1, vf1, oacc[mt], 0, 0, 0);
            }
        }

        if (kt < NT - 1) { kcommit(cur ^ 1); vcommit(cur ^ 1); }
        __syncthreads();   // B: next-tile K/V^T staged; Ps free to overwrite
    }

    #pragma unroll
    for (int mt = 0; mt < 4; ++mt)
        #pragma unroll
        for (int r = 0; r < 4; ++r)
            outp[(size_t)(b * LL + q0 + mt * 16 + lg * 4 + r) * DD + 16 * w + lr] = oacc[mt][r];
}

extern "C" void kernel_launch(void* const* d_in, const int* in_sizes, int n_in,
                              void* d_out, int out_size, void* d_ws, size_t ws_size,
                              hipStream_t stream) {
    const float* q = (const float*)d_in[0];
    const float* k = (const float*)d_in[1];
    const float* v = (const float*)d_in[2];
    const void* mask = d_in[3];
    float* attn = (float*)d_out;
    float* outp = attn + (size_t)BB * LL * LL;
    uint32_t* flagp = (uint32_t*)d_ws;

    detect_mask_kernel<<<1, 256, 0, stream>>>((const uint32_t*)mask, flagp);
    fused_attn_kernel<<<dim3((LL / 64) * BB), 256, 0, stream>>>(q, k, v, mask, flagp, attn, outp);
}